// Round 1
// baseline (120.751 us; speedup 1.0000x reference)
//
#include <hip/hip_runtime.h>
#include <math.h>

// Problem constants (match reference)
#define N_PTS_C 32768
#define M_PTS_C 8192
#define EDGES_C (M_PTS_C * 64)
#define CH 35            // C_IN + 3
#define COUT 64
#define NR 4             // rings
#define KI (NR * CH)     // 140
#define CAP 64           // max valid edges stored per center (valid ~ Poisson(2.1))
#define RCUT 0.2f
#define SIG_INV 20.0f    // 1/sigma, sigma = R/N_RINGS = 0.05

// ws layout (bytes):
//   [0,       32768)   cnt[8192]        (int, memset to 0 each launch)
//   [32768,   33024)   mu[64]           (float)
//   [33024,   33280)   rsig[64]         (float)
//   [33280,   4227584) rec[8192*64]     (int2: src, dist-bits)
//   [4227584, 6324736) a[8192*64]       (float, pre-BN aggregated)

__global__ __launch_bounds__(256) void k_edge(
    const float* __restrict__ pos, const int* __restrict__ idx,
    const int* __restrict__ esrc, const int* __restrict__ edst,
    int* __restrict__ cnt, int2* __restrict__ rec)
{
    int e = blockIdx.x * 256 + threadIdx.x;
    int src = esrc[e];
    int dst = edst[e];
    int cpt = idx[dst];
    float dx = pos[src*3+0] - pos[cpt*3+0];
    float dy = pos[src*3+1] - pos[cpt*3+1];
    float dz = pos[src*3+2] - pos[cpt*3+2];
    float dist = sqrtf(dx*dx + dy*dy + dz*dz + 1e-12f);
    if (dist <= RCUT) {
        int slot = atomicAdd(&cnt[dst], 1);
        if (slot < CAP) rec[dst*CAP + slot] = make_int2(src, __float_as_int(dist));
    }
}

// 16 centers per block of 256 threads.
// Phase 2: 16 threads/center accumulate F[140] (each thread owns ki = lane+16u).
// Phase 3: 4 groups of 64 threads; group g round r computes all 64 outputs of
//          center r*4+g via LDS matvec (W stride-35 rows: conflict-free).
__global__ __launch_bounds__(256) void k_center(
    const float* __restrict__ x, const float* __restrict__ pos,
    const float* __restrict__ W, const int* __restrict__ cnt,
    const int2* __restrict__ rec, float* __restrict__ aout)
{
    __shared__ float Wl[KI * COUT];     // 8960 floats, layout [k][o][i]
    __shared__ float Fl[16][KI];        // per-center F
    __shared__ int   nvl[16];

    int tid = threadIdx.x;
    for (int t = tid; t < KI * COUT; t += 256) Wl[t] = W[t];

    int m0 = blockIdx.x * 16;
    int c = tid >> 4;
    int lane = tid & 15;
    int m = m0 + c;
    int nv = min(cnt[m], CAP);
    if (lane == 0) nvl[c] = nv;

    float facc[9];
    #pragma unroll
    for (int u = 0; u < 9; ++u) facc[u] = 0.f;

    for (int j = 0; j < nv; ++j) {
        int2 r = rec[m*CAP + j];
        int src = r.x;
        float dist = __int_as_float(r.y);
        float t0 = dist * SIG_INV;
        float t1 = (dist - (float)(0.2/3.0)) * SIG_INV;
        float t2 = (dist - (float)(0.4/3.0)) * SIG_INV;
        float t3 = (dist - 0.2f) * SIG_INV;
        float b0 = expf(-0.5f*t0*t0);
        float b1 = expf(-0.5f*t1*t1);
        float b2 = expf(-0.5f*t2*t2);
        float b3 = expf(-0.5f*t3*t3);
        #pragma unroll
        for (int u = 0; u < 9; ++u) {
            int ki = lane + u*16;
            if (ki < KI) {
                int k = ki / CH;
                int i = ki - k*CH;
                float hv = (i < 32) ? x[src*32 + i] : pos[src*3 + (i - 32)];
                float bk = (k==0) ? b0 : (k==1) ? b1 : (k==2) ? b2 : b3;
                facc[u] += bk * hv;
            }
        }
    }
    #pragma unroll
    for (int u = 0; u < 9; ++u) {
        int ki = lane + u*16;
        if (ki < KI) Fl[c][ki] = facc[u];
    }
    __syncthreads();

    int o = tid & 63;
    int g = tid >> 6;
    #pragma unroll 1
    for (int r = 0; r < 4; ++r) {
        int cc = r*4 + g;
        float acc = 0.f;
        #pragma unroll
        for (int k = 0; k < NR; ++k) {
            const float* wrow = &Wl[(k*COUT + o)*CH];
            const float* frow = &Fl[cc][k*CH];
            #pragma unroll
            for (int i = 0; i < CH; ++i) acc += wrow[i] * frow[i];
        }
        float nvf = (float)nvl[cc];
        aout[(m0 + cc)*COUT + o] = acc / fmaxf(nvf, 1.f);
    }
}

// One block per channel: deterministic mean/var (no atomics, no extra memset).
__global__ __launch_bounds__(256) void k_bn(
    const float* __restrict__ a, float* __restrict__ mu, float* __restrict__ rs)
{
    int o = blockIdx.x, t = threadIdx.x;
    float s = 0.f, q = 0.f;
    for (int m = t; m < M_PTS_C; m += 256) {
        float v = a[m*COUT + o];
        s += v; q += v*v;
    }
    __shared__ float ss[256], sq[256];
    ss[t] = s; sq[t] = q;
    __syncthreads();
    for (int w = 128; w >= 1; w >>= 1) {
        if (t < w) { ss[t] += ss[t+w]; sq[t] += sq[t+w]; }
        __syncthreads();
    }
    if (t == 0) {
        float m_ = ss[0] * (1.f / M_PTS_C);
        float v_ = sq[0] * (1.f / M_PTS_C) - m_*m_;
        mu[o] = m_;
        rs[o] = rsqrtf(v_ + 1e-5f);
    }
}

// One thread per (center, field): BN affine + norm nonlinearity, float4 I/O.
__global__ __launch_bounds__(256) void k_post(
    const float* __restrict__ a, const float* __restrict__ mu,
    const float* __restrict__ rs, const float* __restrict__ gamma,
    const float* __restrict__ beta, const float* __restrict__ nbias,
    float* __restrict__ out)
{
    int flat = blockIdx.x * 256 + threadIdx.x;   // [0, M*16)
    int f = flat & 15;
    const float4* a4 = (const float4*)a;
    float4 v = a4[flat];
    float y[4];
    float nn = 1e-12f;
    #pragma unroll
    for (int jj = 0; jj < 4; ++jj) {
        int o = f*4 + jj;
        float val = (jj==0) ? v.x : (jj==1) ? v.y : (jj==2) ? v.z : v.w;
        float yy = (val - mu[o]) * rs[o] * gamma[o] + beta[o];
        y[jj] = yy;
        nn += yy*yy;
    }
    float n = sqrtf(nn);
    float z = n + nbias[f];
    float e = (z > 0.f) ? z : expm1f(z);
    float sc = e / n;
    float4 ov;
    ov.x = y[0]*sc; ov.y = y[1]*sc; ov.z = y[2]*sc; ov.w = y[3]*sc;
    ((float4*)out)[flat] = ov;
}

extern "C" void kernel_launch(void* const* d_in, const int* in_sizes, int n_in,
                              void* d_out, int out_size, void* d_ws, size_t ws_size,
                              hipStream_t stream)
{
    const float* x     = (const float*)d_in[0];
    const float* pos   = (const float*)d_in[1];
    const int*   idx   = (const int*)d_in[2];
    const int*   esrc  = (const int*)d_in[3];
    const int*   edst  = (const int*)d_in[4];
    const float* W     = (const float*)d_in[5];
    const float* gamma = (const float*)d_in[6];
    const float* beta  = (const float*)d_in[7];
    const float* nbias = (const float*)d_in[8];

    char* ws = (char*)d_ws;
    int*   cnt = (int*)ws;
    float* mu  = (float*)(ws + 32768);
    float* rsg = (float*)(ws + 33024);
    int2*  rec = (int2*)(ws + 33280);
    float* a   = (float*)(ws + 4227584);

    hipMemsetAsync(cnt, 0, 32768, stream);
    k_edge<<<EDGES_C/256, 256, 0, stream>>>(pos, idx, esrc, edst, cnt, rec);
    k_center<<<M_PTS_C/16, 256, 0, stream>>>(x, pos, W, cnt, rec, a);
    k_bn<<<COUT, 256, 0, stream>>>(a, mu, rsg);
    k_post<<<(M_PTS_C*16)/256, 256, 0, stream>>>(a, mu, rsg, gamma, beta, nbias, (float*)d_out);
}